// Round 13
// baseline (40.519 us; speedup 1.0000x reference)
//
#include <hip/hip_runtime.h>

// WOMD post-processing FINAL == v10 (measured best: 28.35 us, absmax 0.0).
// 4 agents per wave (16 lanes/agent, 2 modes/lane), 1024 waves, zero LDS.
// Restored verbatim after v11/v12 experiments regressed (42.5/40.0 us).
// Session evidence: all pipes <3% busy, FETCH at structural line minimum,
// wall tracks waves x stream with a large fixed per-wave term -> this shape
// (minimal waves x minimal stream, single dispatch) is the empirical floor.

#define NSC 64
#define NAG 64
#define NJF 32
#define NSTEP 80
#define KP 6
#define TOUT 16

struct F3 { float x, y, z; };

__global__ __launch_bounds__(64)
void womd_pp10(const float* __restrict__ ag_type,
               const float* __restrict__ trajs,
               const float* __restrict__ scores,
               float* __restrict__ out)
{
    const int tid = threadIdx.x;
    const int g   = tid >> 4;              // group 0..3 = agent slot
    const int gl  = tid & 15;              // lane within group
    const int ga  = blockIdx.x * 4 + g;    // global agent 0..4095
    const int s   = ga >> 6;               // scene
    const int a   = ga & 63;               // agent

    // modes owned by this lane: j0 = gl, j1 = gl + 16
    // ---- loads ----
    const float* sp = scores + (size_t)s * NJF * NAG + a;
    float raw0 = sp[(size_t)gl * NAG];
    float raw1 = sp[(size_t)(gl + 16) * NAG];

    const float* tb = trajs + (size_t)s * NJF * NAG * NSTEP * 3;  // scene base
    size_t e0 = (((size_t)gl * NAG + a) * NSTEP + (NSTEP - 1)) * 3;
    size_t e1 = (((size_t)(gl + 16) * NAG + a) * NSTEP + (NSTEP - 1)) * 3;
    float2 p0 = *(const float2*)(tb + e0);     // endpoint of mode j0
    float2 p1 = *(const float2*)(tb + e1);     // endpoint of mode j1

    F3 atv = *(const F3*)(ag_type + (size_t)(s * NAG + a) * 3);
    const float thresh = atv.x * 2.5f + atv.y * 1.0f + atv.z * 2.0f;

    // ---- softmax over 32 modes (16-lane butterfly, 2 modes/lane) ----
    float mx = fmaxf(raw0, raw1);
    #pragma unroll
    for (int off = 8; off > 0; off >>= 1)
        mx = fmaxf(mx, __shfl_xor(mx, off, 16));
    float ev0 = expf(raw0 - mx);
    float ev1 = expf(raw1 - mx);
    float sum = ev0 + ev1;
    #pragma unroll
    for (int off = 8; off > 0; off >>= 1)
        sum += __shfl_xor(sum, off, 16);
    float sm0 = ev0 / sum;
    float sm1 = ev1 / sum;

    // ---- MTR NMS: 6 picks ----
    int   sel[KP];
    float skp[KP], sxp[KP], syp[KP];       // pick score/endpoint (all lanes)
    float ls0 = sm0, ls1 = sm1;
    #pragma unroll
    for (int k = 0; k < KP; ++k) {
        float v = fmaxf(ls0, ls1);
        #pragma unroll
        for (int off = 8; off > 0; off >>= 1)
            v = fmaxf(v, __shfl_xor(v, off, 16));
        // first mode index attaining the max (modes 0-15 before 16-31)
        unsigned long long b0 = __ballot(ls0 == v);
        unsigned long long b1 = __ballot(ls1 == v);
        unsigned m0 = (unsigned)(b0 >> (g * 16)) & 0xFFFFu;
        unsigned m1 = (unsigned)(b1 >> (g * 16)) & 0xFFFFu;
        int idx = m0 ? (__ffs(m0) - 1) : (16 + __ffs(m1) - 1);
        sel[k] = idx;

        // pick endpoint+score broadcast: source-side select, 3 shuffles
        int  il = idx & 15;
        bool lo = (idx < 16);
        float sxv = lo ? p0.x : p1.x;
        float syv = lo ? p0.y : p1.y;
        float skv = lo ? sm0 : sm1;
        float px = __shfl(sxv, il, 16);
        float py = __shfl(syv, il, 16);
        float pk = __shfl(skv, il, 16);
        sxp[k] = px;  syp[k] = py;  skp[k] = pk;

        // within(pick, my modes): sqrtf, strict < (matches reference exactly)
        float dx0 = p0.x - px, dy0 = p0.y - py;
        float dx1 = p1.x - px, dy1 = p1.y - py;
        bool w0 = sqrtf(dx0 * dx0 + dy0 * dy0) < thresh;
        bool w1 = sqrtf(dx1 * dx1 + dy1 * dy1) < thresh;
        ls0 *= w0 ? 0.01f : 1.0f;          // 0.99f+0.01f == 1.0f
        ls1 *= w1 ? 0.01f : 1.0f;
        ls0 = (gl == idx)      ? -1.0f : ls0;
        ls1 = (gl + 16 == idx) ? -1.0f : ls1;
    }

    // ---- trajectory gather: t = gl for all 6 modes; issue before tail ----
    F3 pt[KP];
    #pragma unroll
    for (int i = 0; i < KP; ++i) {
        size_t src = (((size_t)sel[i] * NAG + a) * NSTEP + (4 + 5 * gl)) * 3;
        pt[i] = *(const F3*)(tb + src);
    }

    // ---- MPA tail: redundant on all 16 lanes, registers only ----
    float ssum = 0.f;
    #pragma unroll
    for (int k = 0; k < KP; ++k) ssum += skp[k];
    float sk[KP], sk0[KP];
    #pragma unroll
    for (int k = 0; k < KP; ++k) { sk[k] = skp[k] / ssum; sk0[k] = sk[k]; }

    unsigned w2[KP];
    #pragma unroll
    for (int i = 0; i < KP; ++i) {
        unsigned r = 0;
        #pragma unroll
        for (int j = 0; j < KP; ++j) {
            float dx = sxp[i] - sxp[j], dy = syp[i] - syp[j];
            r |= (sqrtf(dx * dx + dy * dy) < thresh) ? (1u << j) : 0u;
        }
        w2[i] = r;
    }

    // stable descending rank (ties -> lower index)
    int rank[KP];
    #pragma unroll
    for (int j = 0; j < KP; ++j) {
        int r = 0;
        #pragma unroll
        for (int i = 0; i < KP; ++i)
            r += ((sk0[i] > sk0[j]) || (sk0[i] == sk0[j] && i < j)) ? 1 : 0;
        rank[j] = r;
    }

    // sequential MPA scan in rank order (select chains, literal idx only)
    #pragma unroll
    for (int t = 0; t < KP; ++t) {
        float sk_k = sk[0]; unsigned w2k = w2[0];
        #pragma unroll
        for (int j = 1; j < KP; ++j) {
            bool is = (rank[j] == t);
            sk_k = is ? sk[j] : sk_k;
            w2k  = is ? w2[j] : w2k;
        }
        bool any = false;
        #pragma unroll
        for (int j = 0; j < KP; ++j)
            any = any || ((((w2k >> j) & 1u) != 0u) && (sk[j] > sk_k));
        #pragma unroll
        for (int j = 0; j < KP; ++j)
            if (rank[j] == t && any) sk[j] = 0.001f;
    }

    // normalize; softmax(log p / 0.5) == p^2 / sum(p^2)
    float s2 = 0.f;
    #pragma unroll
    for (int k = 0; k < KP; ++k) s2 += sk[k];
    #pragma unroll
    for (int k = 0; k < KP; ++k) sk[k] /= s2;
    float q[KP]; float s3 = 0.f;
    #pragma unroll
    for (int k = 0; k < KP; ++k) { q[k] = sk[k] * sk[k]; s3 += q[k]; }

    // ---- score store: lanes 0-5 of each group, select chain ----
    float qs = q[0] / s3;
    qs = (gl == 1) ? q[1] / s3 : qs;
    qs = (gl == 2) ? q[2] / s3 : qs;
    qs = (gl == 3) ? q[3] / s3 : qs;
    qs = (gl == 4) ? q[4] / s3 : qs;
    qs = (gl == 5) ? q[5] / s3 : qs;
    const size_t SCBASE = (size_t)NSC * NAG * KP * TOUT * 3;
    if (gl < KP) out[SCBASE + (size_t)ga * KP + gl] = qs;

    // ---- trajectory stores: e = 16*i + gl (mode i, step gl) ----
    size_t ob = (size_t)ga * (KP * TOUT * 3);
    #pragma unroll
    for (int i = 0; i < KP; ++i)
        *(F3*)(out + ob + (size_t)(16 * i + gl) * 3) = pt[i];
}

extern "C" void kernel_launch(void* const* d_in, const int* in_sizes, int n_in,
                              void* d_out, int out_size, void* d_ws, size_t ws_size,
                              hipStream_t stream) {
    const float* ag_type = (const float*)d_in[0];
    const float* trajs   = (const float*)d_in[1];
    const float* scores  = (const float*)d_in[2];
    float* out = (float*)d_out;

    womd_pp10<<<NSC * NAG / 4, 64, 0, stream>>>(ag_type, trajs, scores, out);
}

// Round 14
// 28.120 us; speedup vs baseline: 1.4409x; 1.4409x over previous
//
#include <hip/hip_runtime.h>

// WOMD post-processing FINAL == v10 (third sample / tie-breaker).
// Identical code measured 28.35 us (R9) and 40.5 us (R12) while BW-bound
// fill dispatches stayed stable across all rounds -> ±30% session-level
// variance specific to latency-bound kernels (clock/node state).
// 4 agents per wave (16 lanes/agent, 2 modes/lane), 1024 waves, zero LDS,
// single dispatch. All pipes <3% busy; FETCH at structural line minimum.

#define NSC 64
#define NAG 64
#define NJF 32
#define NSTEP 80
#define KP 6
#define TOUT 16

struct F3 { float x, y, z; };

__global__ __launch_bounds__(64)
void womd_pp10(const float* __restrict__ ag_type,
               const float* __restrict__ trajs,
               const float* __restrict__ scores,
               float* __restrict__ out)
{
    const int tid = threadIdx.x;
    const int g   = tid >> 4;              // group 0..3 = agent slot
    const int gl  = tid & 15;              // lane within group
    const int ga  = blockIdx.x * 4 + g;    // global agent 0..4095
    const int s   = ga >> 6;               // scene
    const int a   = ga & 63;               // agent

    // modes owned by this lane: j0 = gl, j1 = gl + 16
    // ---- loads ----
    const float* sp = scores + (size_t)s * NJF * NAG + a;
    float raw0 = sp[(size_t)gl * NAG];
    float raw1 = sp[(size_t)(gl + 16) * NAG];

    const float* tb = trajs + (size_t)s * NJF * NAG * NSTEP * 3;  // scene base
    size_t e0 = (((size_t)gl * NAG + a) * NSTEP + (NSTEP - 1)) * 3;
    size_t e1 = (((size_t)(gl + 16) * NAG + a) * NSTEP + (NSTEP - 1)) * 3;
    float2 p0 = *(const float2*)(tb + e0);     // endpoint of mode j0
    float2 p1 = *(const float2*)(tb + e1);     // endpoint of mode j1

    F3 atv = *(const F3*)(ag_type + (size_t)(s * NAG + a) * 3);
    const float thresh = atv.x * 2.5f + atv.y * 1.0f + atv.z * 2.0f;

    // ---- softmax over 32 modes (16-lane butterfly, 2 modes/lane) ----
    float mx = fmaxf(raw0, raw1);
    #pragma unroll
    for (int off = 8; off > 0; off >>= 1)
        mx = fmaxf(mx, __shfl_xor(mx, off, 16));
    float ev0 = expf(raw0 - mx);
    float ev1 = expf(raw1 - mx);
    float sum = ev0 + ev1;
    #pragma unroll
    for (int off = 8; off > 0; off >>= 1)
        sum += __shfl_xor(sum, off, 16);
    float sm0 = ev0 / sum;
    float sm1 = ev1 / sum;

    // ---- MTR NMS: 6 picks ----
    int   sel[KP];
    float skp[KP], sxp[KP], syp[KP];       // pick score/endpoint (all lanes)
    float ls0 = sm0, ls1 = sm1;
    #pragma unroll
    for (int k = 0; k < KP; ++k) {
        float v = fmaxf(ls0, ls1);
        #pragma unroll
        for (int off = 8; off > 0; off >>= 1)
            v = fmaxf(v, __shfl_xor(v, off, 16));
        // first mode index attaining the max (modes 0-15 before 16-31)
        unsigned long long b0 = __ballot(ls0 == v);
        unsigned long long b1 = __ballot(ls1 == v);
        unsigned m0 = (unsigned)(b0 >> (g * 16)) & 0xFFFFu;
        unsigned m1 = (unsigned)(b1 >> (g * 16)) & 0xFFFFu;
        int idx = m0 ? (__ffs(m0) - 1) : (16 + __ffs(m1) - 1);
        sel[k] = idx;

        // pick endpoint+score broadcast: source-side select, 3 shuffles
        int  il = idx & 15;
        bool lo = (idx < 16);
        float sxv = lo ? p0.x : p1.x;
        float syv = lo ? p0.y : p1.y;
        float skv = lo ? sm0 : sm1;
        float px = __shfl(sxv, il, 16);
        float py = __shfl(syv, il, 16);
        float pk = __shfl(skv, il, 16);
        sxp[k] = px;  syp[k] = py;  skp[k] = pk;

        // within(pick, my modes): sqrtf, strict < (matches reference exactly)
        float dx0 = p0.x - px, dy0 = p0.y - py;
        float dx1 = p1.x - px, dy1 = p1.y - py;
        bool w0 = sqrtf(dx0 * dx0 + dy0 * dy0) < thresh;
        bool w1 = sqrtf(dx1 * dx1 + dy1 * dy1) < thresh;
        ls0 *= w0 ? 0.01f : 1.0f;          // 0.99f+0.01f == 1.0f
        ls1 *= w1 ? 0.01f : 1.0f;
        ls0 = (gl == idx)      ? -1.0f : ls0;
        ls1 = (gl + 16 == idx) ? -1.0f : ls1;
    }

    // ---- trajectory gather: t = gl for all 6 modes; issue before tail ----
    F3 pt[KP];
    #pragma unroll
    for (int i = 0; i < KP; ++i) {
        size_t src = (((size_t)sel[i] * NAG + a) * NSTEP + (4 + 5 * gl)) * 3;
        pt[i] = *(const F3*)(tb + src);
    }

    // ---- MPA tail: redundant on all 16 lanes, registers only ----
    float ssum = 0.f;
    #pragma unroll
    for (int k = 0; k < KP; ++k) ssum += skp[k];
    float sk[KP], sk0[KP];
    #pragma unroll
    for (int k = 0; k < KP; ++k) { sk[k] = skp[k] / ssum; sk0[k] = sk[k]; }

    unsigned w2[KP];
    #pragma unroll
    for (int i = 0; i < KP; ++i) {
        unsigned r = 0;
        #pragma unroll
        for (int j = 0; j < KP; ++j) {
            float dx = sxp[i] - sxp[j], dy = syp[i] - syp[j];
            r |= (sqrtf(dx * dx + dy * dy) < thresh) ? (1u << j) : 0u;
        }
        w2[i] = r;
    }

    // stable descending rank (ties -> lower index)
    int rank[KP];
    #pragma unroll
    for (int j = 0; j < KP; ++j) {
        int r = 0;
        #pragma unroll
        for (int i = 0; i < KP; ++i)
            r += ((sk0[i] > sk0[j]) || (sk0[i] == sk0[j] && i < j)) ? 1 : 0;
        rank[j] = r;
    }

    // sequential MPA scan in rank order (select chains, literal idx only)
    #pragma unroll
    for (int t = 0; t < KP; ++t) {
        float sk_k = sk[0]; unsigned w2k = w2[0];
        #pragma unroll
        for (int j = 1; j < KP; ++j) {
            bool is = (rank[j] == t);
            sk_k = is ? sk[j] : sk_k;
            w2k  = is ? w2[j] : w2k;
        }
        bool any = false;
        #pragma unroll
        for (int j = 0; j < KP; ++j)
            any = any || ((((w2k >> j) & 1u) != 0u) && (sk[j] > sk_k));
        #pragma unroll
        for (int j = 0; j < KP; ++j)
            if (rank[j] == t && any) sk[j] = 0.001f;
    }

    // normalize; softmax(log p / 0.5) == p^2 / sum(p^2)
    float s2 = 0.f;
    #pragma unroll
    for (int k = 0; k < KP; ++k) s2 += sk[k];
    #pragma unroll
    for (int k = 0; k < KP; ++k) sk[k] /= s2;
    float q[KP]; float s3 = 0.f;
    #pragma unroll
    for (int k = 0; k < KP; ++k) { q[k] = sk[k] * sk[k]; s3 += q[k]; }

    // ---- score store: lanes 0-5 of each group, select chain ----
    float qs = q[0] / s3;
    qs = (gl == 1) ? q[1] / s3 : qs;
    qs = (gl == 2) ? q[2] / s3 : qs;
    qs = (gl == 3) ? q[3] / s3 : qs;
    qs = (gl == 4) ? q[4] / s3 : qs;
    qs = (gl == 5) ? q[5] / s3 : qs;
    const size_t SCBASE = (size_t)NSC * NAG * KP * TOUT * 3;
    if (gl < KP) out[SCBASE + (size_t)ga * KP + gl] = qs;

    // ---- trajectory stores: e = 16*i + gl (mode i, step gl) ----
    size_t ob = (size_t)ga * (KP * TOUT * 3);
    #pragma unroll
    for (int i = 0; i < KP; ++i)
        *(F3*)(out + ob + (size_t)(16 * i + gl) * 3) = pt[i];
}

extern "C" void kernel_launch(void* const* d_in, const int* in_sizes, int n_in,
                              void* d_out, int out_size, void* d_ws, size_t ws_size,
                              hipStream_t stream) {
    const float* ag_type = (const float*)d_in[0];
    const float* trajs   = (const float*)d_in[1];
    const float* scores  = (const float*)d_in[2];
    float* out = (float*)d_out;

    womd_pp10<<<NSC * NAG / 4, 64, 0, stream>>>(ag_type, trajs, scores, out);
}